// Round 11
// baseline (7597.101 us; speedup 1.0000x reference)
//
#include <hip/hip_runtime.h>

// Problem constants (from reference): B=32, T=2048, D_IN=D_OUT=512, fp32.
constexpr int B = 32, T = 2048, D = 512;

typedef float f32x4 __attribute__((ext_vector_type(4)));

// ---------------- Kernel 1: xw = x @ W + b, written in-place into d_out ----
__global__ __launch_bounds__(256) void xw_gemm(
    const float* __restrict__ A, const float* __restrict__ W,
    const float* __restrict__ bias, float* __restrict__ C) {
  __shared__ float As[16][68];
  __shared__ float Bs[16][68];
  const int tid = threadIdx.x;
  const int M0 = blockIdx.y * 64, N0 = blockIdx.x * 64;
  const int tn = tid & 15, tm = tid >> 4;
  const int rA = tid >> 2, kA = (tid & 3) << 2;
  const int kB = tid >> 4, nB = (tid & 15) << 2;
  float acc[4][4] = {};
  for (int k0 = 0; k0 < 512; k0 += 16) {
    float4 a4 = *(const float4*)&A[(size_t)(M0 + rA) * 512 + k0 + kA];
    As[kA + 0][rA] = a4.x;
    As[kA + 1][rA] = a4.y;
    As[kA + 2][rA] = a4.z;
    As[kA + 3][rA] = a4.w;
    *(float4*)&Bs[kB][nB] = *(const float4*)&W[(size_t)(k0 + kB) * 512 + N0 + nB];
    __syncthreads();
#pragma unroll
    for (int k = 0; k < 16; ++k) {
      float a0 = As[k][tm * 4 + 0], a1 = As[k][tm * 4 + 1];
      float a2 = As[k][tm * 4 + 2], a3 = As[k][tm * 4 + 3];
      float b0 = Bs[k][tn * 4 + 0], b1 = Bs[k][tn * 4 + 1];
      float b2 = Bs[k][tn * 4 + 2], b3 = Bs[k][tn * 4 + 3];
      acc[0][0] += a0 * b0; acc[0][1] += a0 * b1; acc[0][2] += a0 * b2; acc[0][3] += a0 * b3;
      acc[1][0] += a1 * b0; acc[1][1] += a1 * b1; acc[1][2] += a1 * b2; acc[1][3] += a1 * b3;
      acc[2][0] += a2 * b0; acc[2][1] += a2 * b1; acc[2][2] += a2 * b2; acc[2][3] += a2 * b3;
      acc[3][0] += a3 * b0; acc[3][1] += a3 * b1; acc[3][2] += a3 * b2; acc[3][3] += a3 * b3;
    }
    __syncthreads();
  }
#pragma unroll
  for (int i = 0; i < 4; ++i) {
    const size_t row = (size_t)(M0 + tm * 4 + i);
    float4 v;
    v.x = acc[i][0] + bias[N0 + tn * 4 + 0];
    v.y = acc[i][1] + bias[N0 + tn * 4 + 1];
    v.z = acc[i][2] + bias[N0 + tn * 4 + 2];
    v.w = acc[i][3] + bias[N0 + tn * 4 + 3];
    *(float4*)&C[row * 512 + N0 + tn * 4] = v;
  }
}

// ---------------- Kernel 2: 4-phase scan with counted vmcnt waits ----------
// 64 blocks x 512 thr = 8 cliques x 8 blocks; clique owns 4 batches, block
// owns 64 cols. Thread: (cp=tid>>4, kq=tid&15) -> cols {C0+cp, C0+cp+32},
// 32 k; W via volatile asm loads (remat-proof, r10). Round = 4 phases, one
// batch each. ALL loop global VMEM goes through asm -> statically counted
// stream [xw][e-pair][2 stores] = 5/phase. Entry wait = vmcnt(8): waits
// ONLY the e-pair pre-issued 2 phases earlier (in-order retirement; >=8
// younger issues on every path) -- never waits publish-store acks (the r10
// per-phase ~0.9us serial cost). xw wait = vmcnt(2). Misses -> vmcnt(0)
// repoll (always correct). Round 1 peeled with vmcnt(0). Transport: sc1
// band-encoded floats (proven r2/r4/r5/r7/r9/r10).
constexpr int NBLK = 64, NTHR = 512;

__device__ __forceinline__ void ld4_issue(const float* p, f32x4& v) {
  asm volatile("global_load_dwordx4 %0, %1, off sc1" : "=&v"(v) : "v"(p) : "memory");
}
__device__ __forceinline__ void ldW(const float* p, float& v) {
  asm volatile("global_load_dword %0, %1, off" : "=&v"(v) : "v"(p) : "memory");
}
__device__ __forceinline__ void st1(float* p, float v) {
  asm volatile("global_store_dword %0, %1, off sc1" ::"v"(p), "v"(v) : "memory");
}
__device__ __forceinline__ int chk(f32x4 v, float off) {
  return (fabsf(v[0] - off) < 1.5f) & (fabsf(v[1] - off) < 1.5f) &
         (fabsf(v[2] - off) < 1.5f) & (fabsf(v[3] - off) < 1.5f);
}

#define XSTR(x) #x

__global__ __launch_bounds__(NTHR, 2) void rnn_scan(
    float* __restrict__ out, const float* __restrict__ Wrec,
    float* __restrict__ xbuf) {
  __shared__ float hb_all[8][512];  // per-wave private h stage
  const int blk = blockIdx.x;
  const int bg = blk >> 3, cg = blk & 7;
  const int C0 = cg * 64;
  const int gb0 = bg * 4;
  const int tid = threadIdx.x;
  const int wv = tid >> 6, lane = tid & 63;
  const int kq = lane & 15;
  const int cp = tid >> 4;
  const int col0 = C0 + cp, col1 = C0 + cp + 32;
  const int mycol = (kq & 1) ? col1 : col0;
  const int kb = kq * 32;
  const int swz = (kq & 7) << 2;
  const int sg = lane * 8;  // this lane stages h[sg..sg+8)
  const int sgx0 = sg ^ (((sg >> 5) & 7) << 2);
  const int sgx1 = (sg + 4) ^ ((((sg + 4) >> 5) & 7) << 2);
  float* hb = hb_all[wv];

  // ---- W into regs via volatile asm loads (cannot be rematerialized) ----
  float w0[32], w1[32];
  {
    const float* p0 = Wrec + (size_t)kb * D + col0;
    const float* p1 = Wrec + (size_t)kb * D + col1;
#pragma unroll
    for (int i = 0; i < 32; ++i) {
      ldW(p0 + (size_t)i * D, w0[i]);
      ldW(p1 + (size_t)i * D, w1[i]);
    }
    asm volatile("s_waitcnt vmcnt(0)" ::: "memory");
  }

  float* xcl = xbuf + (size_t)bg * 4096;  // [parity(2)][batch(4)][512]

  // ---- t = 0: lanes kq<8 handle (s=kq>>1, col=kq&1); publish parity 0 -----
  if (kq < 8) {
    const int s0 = kq >> 1;
    const int cc = (kq & 1) ? col1 : col0;
    const size_t o = ((size_t)(gb0 + s0) * T) * D + cc;
    const float h = tanhf(out[o]);
    out[o] = h;
    st1(xcl + s0 * 512 + cc, h + 3.0f);
  }
  // pre-issue e for round-1 phases 0 and 1 (parity 0)
  f32x4 eA0, eA1, eB0, eB1;
  ld4_issue(xcl + 0 * 512 + sg, eA0);
  ld4_issue(xcl + 0 * 512 + sg + 4, eA1);
  ld4_issue(xcl + 1 * 512 + sg, eB0);
  ld4_issue(xcl + 1 * 512 + sg + 4, eB1);

  // PHASE: consume (pvo,S) in E; pre-issue (PIO,SI) into E; publish (pwo,S).
#define PHASE(WN, S, SI, PIO, E0, E1)                                         \
  {                                                                           \
    const float* xp = &out[((size_t)(gb0 + (S)) * T + r) * D + mycol];        \
    float xwv;                                                                \
    asm volatile("global_load_dword %0, %1, off" : "=&v"(xwv) : "v"(xp)       \
                 : "memory");                                                 \
    asm volatile("s_waitcnt vmcnt(" XSTR(WN) ")"                              \
                 : "+v"(E0), "+v"(E1)::"memory");                             \
    __builtin_amdgcn_sched_barrier(0);                                        \
    int ok = chk(E0, offR) & chk(E1, offR);                                   \
    if (!__all(ok)) {                                                         \
      const float* sp = xcl + pvo + (S)*512 + sg;                             \
      do {                                                                    \
        ld4_issue(sp, E0);                                                    \
        ld4_issue(sp + 4, E1);                                                \
        asm volatile("s_waitcnt vmcnt(0)" : "+v"(E0), "+v"(E1)::"memory");    \
        __builtin_amdgcn_sched_barrier(0);                                    \
        ok = chk(E0, offR) & chk(E1, offR);                                   \
      } while (!__all(ok));                                                   \
    }                                                                         \
    *(f32x4*)&hb[sgx0] = E0 - offR;                                           \
    *(f32x4*)&hb[sgx1] = E1 - offR;                                           \
    ld4_issue(xcl + (PIO) + (SI)*512 + sg, E0);                               \
    ld4_issue(xcl + (PIO) + (SI)*512 + sg + 4, E1);                           \
    float a0 = 0.f, a1 = 0.f;                                                 \
    _Pragma("unroll") for (int i4 = 0; i4 < 8; ++i4) {                        \
      const f32x4 h4 = *(const f32x4*)&hb[(kb + 4 * i4) ^ swz];               \
      _Pragma("unroll") for (int j = 0; j < 4; ++j) {                         \
        a0 += w0[4 * i4 + j] * h4[j];                                         \
        a1 += w1[4 * i4 + j] * h4[j];                                         \
      }                                                                       \
    }                                                                         \
    a0 += __shfl_xor(a0, 1); a1 += __shfl_xor(a1, 1);                         \
    a0 += __shfl_xor(a0, 2); a1 += __shfl_xor(a1, 2);                         \
    a0 += __shfl_xor(a0, 4); a1 += __shfl_xor(a1, 4);                         \
    a0 += __shfl_xor(a0, 8); a1 += __shfl_xor(a1, 8);                         \
    asm volatile("s_waitcnt vmcnt(2)" : "+v"(xwv)::"memory");                 \
    __builtin_amdgcn_sched_barrier(0);                                        \
    if (kq < 2) {                                                             \
      const float h = tanhf(((kq == 0) ? a0 : a1) + xwv);                     \
      asm volatile("global_store_dword %0, %1, off" ::"v"(xp), "v"(h)         \
                   : "memory");                                               \
      st1(xcl + pwo + (S)*512 + mycol, h + offW);                             \
    }                                                                         \
  }

#define ROUND(WN)                                                             \
  {                                                                           \
    const int pvo = ((r - 1) & 1) * 2048, pwo = (r & 1) * 2048;               \
    const int iR = (r - 1) & 3, iW = r & 3;                                   \
    const float offR = ((iR & 1) ? 9.f : 3.f) * ((iR & 2) ? -1.f : 1.f);      \
    const float offW = ((iW & 1) ? 9.f : 3.f) * ((iW & 2) ? -1.f : 1.f);      \
    PHASE(WN, 0, 2, pvo, eA0, eA1)                                            \
    PHASE(WN, 1, 3, pvo, eB0, eB1)                                            \
    PHASE(WN, 2, 0, pwo, eA0, eA1)                                            \
    PHASE(WN, 3, 1, pwo, eB0, eB1)                                            \
  }

  int r = 1;
  ROUND(0)  // peeled: vmcnt(0) waits establish the steady VMEM stream
  for (r = 2; r < T; ++r) ROUND(8)

#undef PHASE
#undef ROUND
}

extern "C" void kernel_launch(void* const* d_in, const int* in_sizes, int n_in,
                              void* d_out, int out_size, void* d_ws, size_t ws_size,
                              hipStream_t stream) {
  const float* x = (const float*)d_in[0];
  const float* W = (const float*)d_in[1];
  const float* Wrec = (const float*)d_in[2];
  const float* bias = (const float*)d_in[3];
  float* out = (float*)d_out;

  // xw + bias straight into d_out (row = b*T+t matches [B][T][D]).
  xw_gemm<<<dim3(D / 64, (B * T) / 64), 256, 0, stream>>>(x, W, bias, out);

  // xbuf: 8 cliques x 2 parities x 4 batches x 512 floats = 128 KB.
  // Zeroed every launch (zero is in no band) -> deterministic replays.
  hipMemsetAsync(d_ws, 0, 131072, stream);
  float* xbuf = (float*)d_ws;

  void* args[] = {(void*)&out, (void*)&Wrec, (void*)&xbuf};
  hipLaunchCooperativeKernel(reinterpret_cast<void*>(rnn_scan), dim3(NBLK),
                             dim3(NTHR), args, 0, stream);
}

// Round 12
// 5534.398 us; speedup vs baseline: 1.3727x; 1.3727x over previous
//
#include <hip/hip_runtime.h>

// Problem constants (from reference): B=32, T=2048, D_IN=D_OUT=512, fp32.
constexpr int B = 32, T = 2048, D = 512;

typedef float f32x4 __attribute__((ext_vector_type(4)));

// ---------------- Kernel 1: xw = x @ W + b, written in-place into d_out ----
__global__ __launch_bounds__(256) void xw_gemm(
    const float* __restrict__ A, const float* __restrict__ W,
    const float* __restrict__ bias, float* __restrict__ C) {
  __shared__ float As[16][68];
  __shared__ float Bs[16][68];
  const int tid = threadIdx.x;
  const int M0 = blockIdx.y * 64, N0 = blockIdx.x * 64;
  const int tn = tid & 15, tm = tid >> 4;
  const int rA = tid >> 2, kA = (tid & 3) << 2;
  const int kB = tid >> 4, nB = (tid & 15) << 2;
  float acc[4][4] = {};
  for (int k0 = 0; k0 < 512; k0 += 16) {
    float4 a4 = *(const float4*)&A[(size_t)(M0 + rA) * 512 + k0 + kA];
    As[kA + 0][rA] = a4.x;
    As[kA + 1][rA] = a4.y;
    As[kA + 2][rA] = a4.z;
    As[kA + 3][rA] = a4.w;
    *(float4*)&Bs[kB][nB] = *(const float4*)&W[(size_t)(k0 + kB) * 512 + N0 + nB];
    __syncthreads();
#pragma unroll
    for (int k = 0; k < 16; ++k) {
      float a0 = As[k][tm * 4 + 0], a1 = As[k][tm * 4 + 1];
      float a2 = As[k][tm * 4 + 2], a3 = As[k][tm * 4 + 3];
      float b0 = Bs[k][tn * 4 + 0], b1 = Bs[k][tn * 4 + 1];
      float b2 = Bs[k][tn * 4 + 2], b3 = Bs[k][tn * 4 + 3];
      acc[0][0] += a0 * b0; acc[0][1] += a0 * b1; acc[0][2] += a0 * b2; acc[0][3] += a0 * b3;
      acc[1][0] += a1 * b0; acc[1][1] += a1 * b1; acc[1][2] += a1 * b2; acc[1][3] += a1 * b3;
      acc[2][0] += a2 * b0; acc[2][1] += a2 * b1; acc[2][2] += a2 * b2; acc[2][3] += a2 * b3;
      acc[3][0] += a3 * b0; acc[3][1] += a3 * b1; acc[3][2] += a3 * b2; acc[3][3] += a3 * b3;
    }
    __syncthreads();
  }
#pragma unroll
  for (int i = 0; i < 4; ++i) {
    const size_t row = (size_t)(M0 + tm * 4 + i);
    float4 v;
    v.x = acc[i][0] + bias[N0 + tn * 4 + 0];
    v.y = acc[i][1] + bias[N0 + tn * 4 + 1];
    v.z = acc[i][2] + bias[N0 + tn * 4 + 2];
    v.w = acc[i][3] + bias[N0 + tn * 4 + 3];
    *(float4*)&C[row * 512 + N0 + tn * 4] = v;
  }
}

// ---------------- Kernel 2: per-batch clique scan, single phase/step -------
// 256 blocks x 512 thr = 32 cliques (one per BATCH) x 8 blocks (64 cols).
// Thread (cp=tid>>5 -> 4 cols, kq=tid&31 -> 16 k): W = 16 f32x4 volatile
// loads (~105 VGPR < 256 budget from amdgpu_waves_per_eu(1,2) -> no spill,
// the r5..r11 defect). Per step: ONE dword poll/thread (sc1, IC — the
// transport proven r2..r11), stage to LDS (XOR-swizzled), barrier, 64 FMA,
// 5-round shfl reduce, publish. Per-wave VMEM order is fixed:
// [e][out-st][band-st][xw-ld] -> step entry waits vmcnt(3) (e only, never
// store acks), publish waits vmcnt(1) (xw), miss-repolls use vmcnt(0).
// xw prefetched one step ahead. Cliques are fully independent.
constexpr int NBLK = 256, NTHR = 512;

__device__ __forceinline__ void vld1(const float* p, float& v) {
  asm volatile("global_load_dword %0, %1, off sc1" : "=&v"(v) : "v"(p) : "memory");
}
__device__ __forceinline__ void vld4(const float* p, f32x4& v) {
  asm volatile("global_load_dwordx4 %0, %1, off" : "=&v"(v) : "v"(p) : "memory");
}
__device__ __forceinline__ void vst4(float* p, f32x4 v) {
  asm volatile("global_store_dwordx4 %0, %1, off" ::"v"(p), "v"(v) : "memory");
}
__device__ __forceinline__ void vst4_sc1(float* p, f32x4 v) {
  asm volatile("global_store_dwordx4 %0, %1, off sc1" ::"v"(p), "v"(v) : "memory");
}

__global__ __launch_bounds__(NTHR)
__attribute__((amdgpu_waves_per_eu(1, 2)))
void rnn_scan(float* __restrict__ out, const float* __restrict__ Wrec,
              float* __restrict__ xbuf) {
  __shared__ float hs[2][512];  // h_{t-1}, parity double-buffered, swizzled
  const int blk = blockIdx.x;
  const int batch = blk >> 3;  // clique == batch
  const int cg = blk & 7;
  const int tid = threadIdx.x;
  const int kq = tid & 31;     // k-slice: 16 k
  const int cp = tid >> 5;     // col group: 4 cols
  const int k0 = kq * 16;
  const int col0 = cg * 64 + cp * 4;
  const int swz = (kq & 7) << 2;
  const int spos = tid ^ (((tid >> 4) & 7) << 2);  // stage position (swz(tid))
  const bool pub = (kq == 0);

  // W slice: wv[i] = Wrec[(k0+i)*D + col0..+3], volatile loads
  f32x4 wv[16];
#pragma unroll
  for (int i = 0; i < 16; ++i) vld4(&Wrec[(size_t)(k0 + i) * D + col0], wv[i]);
  asm volatile("s_waitcnt vmcnt(0)" ::: "memory");

  float* slab = xbuf + (size_t)batch * 1024;  // [parity(2)][512]
  float* op = out + (size_t)batch * T * D;

  f32x4 xw4;
  float e;
  // ---- t = 0: h0 = tanh(xw_0); establish the [e][out][band][xw] stream ----
  {
    f32x4 h0 = {0.f, 0.f, 0.f, 0.f};
    if (pub) {
      f32x4 x0;
      vld4(&op[col0], x0);
      asm volatile("s_waitcnt vmcnt(0)" : "+v"(x0)::"memory");
      h0[0] = tanhf(x0[0]); h0[1] = tanhf(x0[1]);
      h0[2] = tanhf(x0[2]); h0[3] = tanhf(x0[3]);
    }
    vld1(&slab[tid], e);  // pre-issue e for r=1 (parity 0)
    if (pub) {
      vst4(&op[col0], h0);
      vst4_sc1(&slab[col0], h0 + 3.0f);           // band off(0)=+3
      vld4(&op[(size_t)1 * D + col0], xw4);       // xw for r=1
    }
  }

  for (int r = 1; r < T; ++r) {
    const int pv = (r - 1) & 1, pw = r & 1;
    const int iR = (r - 1) & 3, iW = r & 3;
    const float offR = ((iR & 1) ? 9.f : 3.f) * ((iR & 2) ? -1.f : 1.f);
    const float offW = ((iW & 1) ? 9.f : 3.f) * ((iW & 2) ? -1.f : 1.f);

    // ---- poll (entry waits ONLY the pre-issued e; never store acks) ----
    asm volatile("s_waitcnt vmcnt(3)" : "+v"(e)::"memory");
    __builtin_amdgcn_sched_barrier(0);
    if (fabsf(e - offR) >= 1.5f) {
      const float* pp = &slab[pv * 512 + tid];
      do {
        vld1(pp, e);
        asm volatile("s_waitcnt vmcnt(0)" : "+v"(e)::"memory");
        __builtin_amdgcn_sched_barrier(0);
      } while (fabsf(e - offR) >= 1.5f);
    }
    hs[pv][spos] = e - offR;
    __syncthreads();

    // ---- compute: 4 cols x 16 k, W in regs, h from LDS ----
    f32x4 a = {0.f, 0.f, 0.f, 0.f};
#pragma unroll
    for (int i4 = 0; i4 < 4; ++i4) {
      const f32x4 h4 = *(const f32x4*)&hs[pv][(k0 + 4 * i4) ^ swz];
#pragma unroll
      for (int j = 0; j < 4; ++j) {
        const float hh = h4[j];
        a[0] += wv[4 * i4 + j][0] * hh;
        a[1] += wv[4 * i4 + j][1] * hh;
        a[2] += wv[4 * i4 + j][2] * hh;
        a[3] += wv[4 * i4 + j][3] * hh;
      }
    }
#pragma unroll
    for (int m = 1; m < 32; m <<= 1) {
      a[0] += __shfl_xor(a[0], m);
      a[1] += __shfl_xor(a[1], m);
      a[2] += __shfl_xor(a[2], m);
      a[3] += __shfl_xor(a[3], m);
    }

    // ---- pre-issue next poll, then finalize/publish ----
    vld1(&slab[pw * 512 + tid], e);  // e for step r+1
    if (pub) {
      asm volatile("s_waitcnt vmcnt(1)" : "+v"(xw4)::"memory");  // xw arrived
      f32x4 h;
      h[0] = tanhf(a[0] + xw4[0]);
      h[1] = tanhf(a[1] + xw4[1]);
      h[2] = tanhf(a[2] + xw4[2]);
      h[3] = tanhf(a[3] + xw4[3]);
      vst4(&op[(size_t)r * D + col0], h);
      vst4_sc1(&slab[pw * 512 + col0], h + offW);
      const int rn = (r + 1 < T) ? (r + 1) : r;
      vld4(&op[(size_t)rn * D + col0], xw4);  // prefetch next xw
    }
  }
}

extern "C" void kernel_launch(void* const* d_in, const int* in_sizes, int n_in,
                              void* d_out, int out_size, void* d_ws, size_t ws_size,
                              hipStream_t stream) {
  const float* x = (const float*)d_in[0];
  const float* W = (const float*)d_in[1];
  const float* Wrec = (const float*)d_in[2];
  const float* bias = (const float*)d_in[3];
  float* out = (float*)d_out;

  // xw + bias straight into d_out (row = b*T+t matches [B][T][D]).
  xw_gemm<<<dim3(D / 64, (B * T) / 64), 256, 0, stream>>>(x, W, bias, out);

  // xbuf: 32 cliques x 2 parities x 512 floats = 128 KB. Zeroed every
  // launch (zero is in no band) -> deterministic replays.
  hipMemsetAsync(d_ws, 0, 131072, stream);
  float* xbuf = (float*)d_ws;

  void* args[] = {(void*)&out, (void*)&Wrec, (void*)&xbuf};
  hipLaunchCooperativeKernel(reinterpret_cast<void*>(rnn_scan), dim3(NBLK),
                             dim3(NTHR), args, 0, stream);
}

// Round 13
// 5119.759 us; speedup vs baseline: 1.4839x; 1.0810x over previous
//
#include <hip/hip_runtime.h>

// Problem constants (from reference): B=32, T=2048, D_IN=D_OUT=512, fp32.
constexpr int B = 32, T = 2048, D = 512;

typedef float f32x4 __attribute__((ext_vector_type(4)));

// ---------------- Kernel 1: xw = x @ W + b, written in-place into d_out ----
__global__ __launch_bounds__(256) void xw_gemm(
    const float* __restrict__ A, const float* __restrict__ W,
    const float* __restrict__ bias, float* __restrict__ C) {
  __shared__ float As[16][68];
  __shared__ float Bs[16][68];
  const int tid = threadIdx.x;
  const int M0 = blockIdx.y * 64, N0 = blockIdx.x * 64;
  const int tn = tid & 15, tm = tid >> 4;
  const int rA = tid >> 2, kA = (tid & 3) << 2;
  const int kB = tid >> 4, nB = (tid & 15) << 2;
  float acc[4][4] = {};
  for (int k0 = 0; k0 < 512; k0 += 16) {
    float4 a4 = *(const float4*)&A[(size_t)(M0 + rA) * 512 + k0 + kA];
    As[kA + 0][rA] = a4.x;
    As[kA + 1][rA] = a4.y;
    As[kA + 2][rA] = a4.z;
    As[kA + 3][rA] = a4.w;
    *(float4*)&Bs[kB][nB] = *(const float4*)&W[(size_t)(k0 + kB) * 512 + N0 + nB];
    __syncthreads();
#pragma unroll
    for (int k = 0; k < 16; ++k) {
      float a0 = As[k][tm * 4 + 0], a1 = As[k][tm * 4 + 1];
      float a2 = As[k][tm * 4 + 2], a3 = As[k][tm * 4 + 3];
      float b0 = Bs[k][tn * 4 + 0], b1 = Bs[k][tn * 4 + 1];
      float b2 = Bs[k][tn * 4 + 2], b3 = Bs[k][tn * 4 + 3];
      acc[0][0] += a0 * b0; acc[0][1] += a0 * b1; acc[0][2] += a0 * b2; acc[0][3] += a0 * b3;
      acc[1][0] += a1 * b0; acc[1][1] += a1 * b1; acc[1][2] += a1 * b2; acc[1][3] += a1 * b3;
      acc[2][0] += a2 * b0; acc[2][1] += a2 * b1; acc[2][2] += a2 * b2; acc[2][3] += a2 * b3;
      acc[3][0] += a3 * b0; acc[3][1] += a3 * b1; acc[3][2] += a3 * b2; acc[3][3] += a3 * b3;
    }
    __syncthreads();
  }
#pragma unroll
  for (int i = 0; i < 4; ++i) {
    const size_t row = (size_t)(M0 + tm * 4 + i);
    float4 v;
    v.x = acc[i][0] + bias[N0 + tn * 4 + 0];
    v.y = acc[i][1] + bias[N0 + tn * 4 + 1];
    v.z = acc[i][2] + bias[N0 + tn * 4 + 2];
    v.w = acc[i][3] + bias[N0 + tn * 4 + 3];
    *(float4*)&C[row * 512 + N0 + tn * 4] = v;
  }
}

// ---------------- Kernel 2: per-batch clique scan (r12) — call-free loop ---
// 256 blocks x 512 thr = 32 cliques (one per BATCH) x 8 blocks (64 cols).
// r12 structure frozen (proven 5.13ms). Fixes: (1) inline tanh (clamp +
// v_exp_f32 + divide) -> NO libcall in the loop, so W stays in VGPRs
// (tanhf's call ABI was spilling everything live, r2..r12's hidden defect);
// (2) amdgpu_waves_per_eu(2,2) -> exact 256-VGPR budget; (3) poll loads use
// "+v" so the register provably holds the OLD band value until data lands
// (band cycling makes stale reads self-rejecting).
constexpr int NBLK = 256, NTHR = 512;

__device__ __forceinline__ float mytanh(float x) {
  const float xc = fminf(fmaxf(x, -9.0f), 9.0f);
  const float t = __builtin_amdgcn_exp2f(xc * 2.885390081777927f);  // e^(2x)
  return 1.0f - 2.0f / (t + 1.0f);
}

__device__ __forceinline__ void vld1(const float* p, float& v) {
  asm volatile("global_load_dword %0, %1, off sc1" : "+v"(v) : "v"(p) : "memory");
}
__device__ __forceinline__ void vld4(const float* p, f32x4& v) {
  asm volatile("global_load_dwordx4 %0, %1, off" : "=&v"(v) : "v"(p) : "memory");
}
__device__ __forceinline__ void vst4(float* p, f32x4 v) {
  asm volatile("global_store_dwordx4 %0, %1, off" ::"v"(p), "v"(v) : "memory");
}
__device__ __forceinline__ void vst4_sc1(float* p, f32x4 v) {
  asm volatile("global_store_dwordx4 %0, %1, off sc1" ::"v"(p), "v"(v) : "memory");
}

__global__ __launch_bounds__(NTHR)
__attribute__((amdgpu_waves_per_eu(2, 2)))
void rnn_scan(float* __restrict__ out, const float* __restrict__ Wrec,
              float* __restrict__ xbuf) {
  __shared__ float hs[2][512];  // h_{t-1}, parity double-buffered, swizzled
  const int blk = blockIdx.x;
  const int batch = blk >> 3;  // clique == batch
  const int cg = blk & 7;
  const int tid = threadIdx.x;
  const int kq = tid & 31;     // k-slice: 16 k
  const int cp = tid >> 5;     // col group: 4 cols
  const int k0 = kq * 16;
  const int col0 = cg * 64 + cp * 4;
  const int swz = (kq & 7) << 2;
  const int spos = tid ^ (((tid >> 4) & 7) << 2);  // stage position (swz(tid))
  const bool pub = (kq == 0);

  // W slice: wv[i] = Wrec[(k0+i)*D + col0..+3], volatile loads (remat-proof)
  f32x4 wv[16];
#pragma unroll
  for (int i = 0; i < 16; ++i) vld4(&Wrec[(size_t)(k0 + i) * D + col0], wv[i]);
  asm volatile("s_waitcnt vmcnt(0)" ::: "memory");

  float* slab = xbuf + (size_t)batch * 1024;  // [parity(2)][512]
  float* op = out + (size_t)batch * T * D;

  f32x4 xw4;
  float e = 1e30f;  // out-of-band until first poll load lands ("+v" binding)
  // ---- t = 0: h0 = tanh(xw_0); establish the [e][out][band][xw] stream ----
  {
    f32x4 h0 = {0.f, 0.f, 0.f, 0.f};
    if (pub) {
      f32x4 x0;
      vld4(&op[col0], x0);
      asm volatile("s_waitcnt vmcnt(0)" : "+v"(x0)::"memory");
      h0[0] = mytanh(x0[0]); h0[1] = mytanh(x0[1]);
      h0[2] = mytanh(x0[2]); h0[3] = mytanh(x0[3]);
    }
    vld1(&slab[tid], e);  // pre-issue e for r=1 (parity 0)
    if (pub) {
      vst4(&op[col0], h0);
      vst4_sc1(&slab[col0], h0 + 3.0f);           // band off(0)=+3
      vld4(&op[(size_t)1 * D + col0], xw4);       // xw for r=1
    }
  }

  for (int r = 1; r < T; ++r) {
    const int pv = (r - 1) & 1, pw = r & 1;
    const int iR = (r - 1) & 3, iW = r & 3;
    const float offR = ((iR & 1) ? 9.f : 3.f) * ((iR & 2) ? -1.f : 1.f);
    const float offW = ((iW & 1) ? 9.f : 3.f) * ((iW & 2) ? -1.f : 1.f);

    // ---- poll (entry waits ONLY the pre-issued e; never store acks) ----
    asm volatile("s_waitcnt vmcnt(3)" : "+v"(e)::"memory");
    __builtin_amdgcn_sched_barrier(0);
    if (fabsf(e - offR) >= 1.5f) {
      const float* pp = &slab[pv * 512 + tid];
      do {
        vld1(pp, e);
        asm volatile("s_waitcnt vmcnt(0)" : "+v"(e)::"memory");
        __builtin_amdgcn_sched_barrier(0);
      } while (fabsf(e - offR) >= 1.5f);
    }
    hs[pv][spos] = e - offR;
    __syncthreads();

    // ---- compute: 4 cols x 16 k, W in regs, h from LDS ----
    f32x4 a = {0.f, 0.f, 0.f, 0.f};
#pragma unroll
    for (int i4 = 0; i4 < 4; ++i4) {
      const f32x4 h4 = *(const f32x4*)&hs[pv][(k0 + 4 * i4) ^ swz];
#pragma unroll
      for (int j = 0; j < 4; ++j) {
        const float hh = h4[j];
        a[0] += wv[4 * i4 + j][0] * hh;
        a[1] += wv[4 * i4 + j][1] * hh;
        a[2] += wv[4 * i4 + j][2] * hh;
        a[3] += wv[4 * i4 + j][3] * hh;
      }
    }
#pragma unroll
    for (int m = 1; m < 32; m <<= 1) {
      a[0] += __shfl_xor(a[0], m);
      a[1] += __shfl_xor(a[1], m);
      a[2] += __shfl_xor(a[2], m);
      a[3] += __shfl_xor(a[3], m);
    }

    // ---- pre-issue next poll, then finalize/publish ----
    vld1(&slab[pw * 512 + tid], e);  // e for step r+1
    if (pub) {
      asm volatile("s_waitcnt vmcnt(1)" : "+v"(xw4)::"memory");  // xw arrived
      f32x4 h;
      h[0] = mytanh(a[0] + xw4[0]);
      h[1] = mytanh(a[1] + xw4[1]);
      h[2] = mytanh(a[2] + xw4[2]);
      h[3] = mytanh(a[3] + xw4[3]);
      vst4(&op[(size_t)r * D + col0], h);
      vst4_sc1(&slab[pw * 512 + col0], h + offW);
      const int rn = (r + 1 < T) ? (r + 1) : r;
      vld4(&op[(size_t)rn * D + col0], xw4);  // prefetch next xw
    }
  }
}

extern "C" void kernel_launch(void* const* d_in, const int* in_sizes, int n_in,
                              void* d_out, int out_size, void* d_ws, size_t ws_size,
                              hipStream_t stream) {
  const float* x = (const float*)d_in[0];
  const float* W = (const float*)d_in[1];
  const float* Wrec = (const float*)d_in[2];
  const float* bias = (const float*)d_in[3];
  float* out = (float*)d_out;

  // xw + bias straight into d_out (row = b*T+t matches [B][T][D]).
  xw_gemm<<<dim3(D / 64, (B * T) / 64), 256, 0, stream>>>(x, W, bias, out);

  // xbuf: 32 cliques x 2 parities x 512 floats = 128 KB. Zeroed every
  // launch (zero is in no band) -> deterministic replays.
  hipMemsetAsync(d_ws, 0, 131072, stream);
  float* xbuf = (float*)d_ws;

  void* args[] = {(void*)&out, (void*)&Wrec, (void*)&xbuf};
  hipLaunchCooperativeKernel(reinterpret_cast<void*>(rnn_scan), dim3(NBLK),
                             dim3(NTHR), args, 0, stream);
}